// Round 1
// 468.166 us; speedup vs baseline: 1.2543x; 1.2543x over previous
//
#include <hip/hip_runtime.h>
#include <hip/hip_fp16.h>

#define MM 8192
#define NN 4096
#define KK 4096
#define BM 256
#define BN 256
#define BK 64
#define NT (KK / BK)   // 64 K-tiles

typedef __attribute__((ext_vector_type(8))) short bf16x8;
typedef __attribute__((ext_vector_type(4))) float floatx4;
typedef __attribute__((ext_vector_type(8))) unsigned short ushort8_t;

typedef const __attribute__((address_space(1))) unsigned int* gptr_t;
typedef __attribute__((address_space(3))) unsigned int* lptr_t;

// round-to-nearest-even fp32 -> bf16 bits (valid for non-NaN inputs)
__device__ __forceinline__ unsigned short f2bf(float f) {
    unsigned u = __builtin_bit_cast(unsigned, f);
    u += 0x7FFFu + ((u >> 16) & 1u);
    return (unsigned short)(u >> 16);
}

__device__ __forceinline__ unsigned short sign_bf16(float f) {
    // sign(clip(fp16(f),-1,1)) == sign(fp16(f)); fp16 rounds |f|<2^-25 to 0
    float h = __half2float(__float2half(f));
    return (h > 0.f) ? 0x3F80u : ((h < 0.f) ? 0xBF80u : 0u);
}

// ---- Prepass 1: x fp32 -> bf16 (row-major M x K), 16B loads / 8B stores ----
__global__ __launch_bounds__(256) void cvt_x_kernel(const float4* __restrict__ x4,
                                                    ushort4* __restrict__ o4, int n4) {
    int i = blockIdx.x * 256 + threadIdx.x;
    if (i >= n4) return;
    float4 v = x4[i];
    ushort4 o;
    o.x = f2bf(v.x); o.y = f2bf(v.y); o.z = f2bf(v.z); o.w = f2bf(v.w);
    o4[i] = o;
}

// ---- Prepass 2: w (K x N fp32) -> sign(fp16(w)) bf16, transposed to N x K ----
__global__ __launch_bounds__(256) void binz_wt_kernel(const float* __restrict__ w,
                                                      unsigned short* __restrict__ wt) {
    __shared__ unsigned short tileT[64][72];   // [n][k]; 144B row stride
    const int n0 = blockIdx.x * 64;
    const int k0 = blockIdx.y * 64;
    const int t  = threadIdx.x;
    {
        const int c4 = t & 15;
        const int rb = t >> 4;
#pragma unroll
        for (int i = 0; i < 4; ++i) {
            int r = rb + i * 16;
            float4 v = *(const float4*)&w[(size_t)(k0 + r) * NN + n0 + c4 * 4];
            tileT[c4 * 4 + 0][r] = sign_bf16(v.x);
            tileT[c4 * 4 + 1][r] = sign_bf16(v.y);
            tileT[c4 * 4 + 2][r] = sign_bf16(v.z);
            tileT[c4 * 4 + 3][r] = sign_bf16(v.w);
        }
    }
    __syncthreads();
    {
        const int g  = t & 7;
        const int nb = t >> 3;
#pragma unroll
        for (int i = 0; i < 2; ++i) {
            int n = nb + i * 32;
            *(ushort8_t*)&wt[(size_t)(n0 + n) * KK + k0 + g * 8] =
                *(const ushort8_t*)&tileT[n][g * 8];
        }
    }
}

// ---- GEMM: 256x256 tile, BK=64, 8 waves, 8-phase pipelined schedule ----
// LDS map (128 KiB): A slots [buf(2)][half(2)] 16 KiB each @ 0..64K,
//                    B slots same @ 64K..128K. Slot = 128 rows x 64 cols bf16,
//                    16B-chunk col swizzled: lds(row, cg) = global(row, cg ^ (row&7)).
// Staging ledger (half order per K-tile: B0,B1,A0,A1):
//   prologue: B0(0) B1(0) A0(0) A1(0) B0(1) B1(1) A0(1); vmcnt(6)
//   tile t: p0 stages A1(t+1); p1: B0(t+2); p2: B1(t+2); p3: A0(t+2)
//   boundary: vmcnt(6) (vmcnt(0) once, entering last tile)
// Read deadlines (slot t's half overwritten at: B0->p1, B1->p2, A0->p3, A1->next p0):
//   B all read @p0; A mf0,1 @p0; mf2,3 @p1; mf4..7 @p2 (quad3 held in regs for p3).
__global__ __launch_bounds__(512, 2) void gemm_bin_kernel(const unsigned short* __restrict__ A,
                                                          const unsigned short* __restrict__ Bt,
                                                          float* __restrict__ C) {
    __shared__ __align__(16) char lds[131072];

    const int tid    = threadIdx.x;
    const int lane   = tid & 63;
    const int wave   = tid >> 6;                       // 0..7
    const int wave_u = __builtin_amdgcn_readfirstlane(wave);
    const int wm     = wave >> 2;                      // 0..1  (128 M-rows each)
    const int wn     = wave & 3;                       // 0..3  (64 N-cols each)
    const int l15    = lane & 15;
    const int kq     = lane >> 4;                      // 0..3

    // XCD-bijective swizzle: 512 wgs, 8 XCDs, 64 contiguous per XCD; n-fast decomp
    const int bid = blockIdx.x;
    const int wg  = (bid & 7) * 64 + (bid >> 3);
    const int bn0 = (wg & 15) * BN;
    const int bm0 = (wg >> 4) * BM;

    // staging address precompute: chunk ch = j*512 + tid; row = ch>>3, cg = ch&7
    // inverse-swizzled global source col: c0 = cg ^ (row&7)
    const int r0 = tid >> 3;                           // 0..63
    const int c0 = (tid & 7) ^ (r0 & 7);
    const char* gA = (const char*)A;
    const char* gB = (const char*)Bt;
    const size_t aoff = (size_t)(bm0 + r0) * (KK * 2) + (size_t)c0 * 16;
    const size_t boff = (size_t)(bn0 + r0) * (KK * 2) + (size_t)c0 * 16;

    __attribute__((address_space(3))) char* lds3 =
        (__attribute__((address_space(3))) char*)lds;
    const int dstw = wave_u * 1024;

    // ds_read swizzled col offsets for k-slice ks: ((ks*4+kq) ^ (lane&7)) * 16
    const int aco0 = ((0 * 4 + kq) ^ (lane & 7)) * 16;
    const int aco1 = ((1 * 4 + kq) ^ (lane & 7)) * 16;
    const char* ldsA_l = lds + l15 * 128;                              // + slot*16K + mf*2048
    const char* ldsB_l = lds + 65536 + ((wn & 1) * 64 + l15) * 128;    // + slot*16K + nf*2048

    floatx4 acc[8][4] = {};
    bf16x8 af[8][2];
    bf16x8 bfr[4][2];

    auto STAGE_A = [&](int h, int kt) {
        const int slot = (kt & 1) * 2 + h;
        const char* s0 = gA + aoff + (size_t)h * (128 * KK * 2) + (size_t)kt * (BK * 2);
        __builtin_amdgcn_global_load_lds((gptr_t)s0,
            (lptr_t)(lds3 + slot * 16384 + dstw), 16, 0, 0);
        __builtin_amdgcn_global_load_lds((gptr_t)(s0 + (size_t)64 * KK * 2),
            (lptr_t)(lds3 + slot * 16384 + 8192 + dstw), 16, 0, 0);
    };
    auto STAGE_B = [&](int h, int kt) {
        const int slot = (kt & 1) * 2 + h;
        const char* s0 = gB + boff + (size_t)h * (128 * KK * 2) + (size_t)kt * (BK * 2);
        __builtin_amdgcn_global_load_lds((gptr_t)s0,
            (lptr_t)(lds3 + 65536 + slot * 16384 + dstw), 16, 0, 0);
        __builtin_amdgcn_global_load_lds((gptr_t)(s0 + (size_t)64 * KK * 2),
            (lptr_t)(lds3 + 65536 + slot * 16384 + 8192 + dstw), 16, 0, 0);
    };
    auto LDA = [&](const char* pA, int mf) {
        af[mf][0] = *(const bf16x8*)(pA + aco0 + mf * 2048);
        af[mf][1] = *(const bf16x8*)(pA + aco1 + mf * 2048);
    };
    auto QUAD = [&](int q) {
#pragma unroll
        for (int mi = 0; mi < 2; ++mi)
#pragma unroll
            for (int nf = 0; nf < 4; ++nf)
#pragma unroll
                for (int ks = 0; ks < 2; ++ks)
                    acc[2 * q + mi][nf] = __builtin_amdgcn_mfma_f32_16x16x32_bf16(
                        af[2 * q + mi][ks], bfr[nf][ks], acc[2 * q + mi][nf], 0, 0, 0);
    };

    // ---- prologue: stage 7 half-tiles, wait tile 0 resident ----
    STAGE_B(0, 0); STAGE_B(1, 0); STAGE_A(0, 0); STAGE_A(1, 0);
    STAGE_B(0, 1); STAGE_B(1, 1); STAGE_A(0, 1);
    asm volatile("s_waitcnt vmcnt(6)" ::: "memory");
    __builtin_amdgcn_s_barrier();

    for (int t = 0; t < NT; ++t) {
        const int buf = t & 1;
        const char* pA = ldsA_l + (buf * 2 + wm) * 16384;
        const char* pB = ldsB_l + (buf * 2 + (wn >> 1)) * 16384;

        // ---- phase 0: read B(all) + A mf0,1 ; stage A1(t+1) ; quad0 ----
#pragma unroll
        for (int nf = 0; nf < 4; ++nf) {
            bfr[nf][0] = *(const bf16x8*)(pB + aco0 + nf * 2048);
            bfr[nf][1] = *(const bf16x8*)(pB + aco1 + nf * 2048);
        }
        LDA(pA, 0); LDA(pA, 1);
        if (t + 1 < NT) STAGE_A(1, t + 1);
        __builtin_amdgcn_s_barrier();
        asm volatile("s_waitcnt lgkmcnt(0)" ::: "memory");
        __builtin_amdgcn_sched_barrier(0);
        __builtin_amdgcn_s_setprio(1);
        QUAD(0);
        __builtin_amdgcn_s_setprio(0);
        __builtin_amdgcn_s_barrier();

        // ---- phase 1: read A mf2,3 ; stage B0(t+2) ; quad1 ----
        LDA(pA, 2); LDA(pA, 3);
        if (t + 2 < NT) STAGE_B(0, t + 2);
        __builtin_amdgcn_s_barrier();
        asm volatile("s_waitcnt lgkmcnt(0)" ::: "memory");
        __builtin_amdgcn_sched_barrier(0);
        __builtin_amdgcn_s_setprio(1);
        QUAD(1);
        __builtin_amdgcn_s_setprio(0);
        __builtin_amdgcn_s_barrier();

        // ---- phase 2: read A mf4..7 ; stage B1(t+2) ; quad2 ----
        LDA(pA, 4); LDA(pA, 5); LDA(pA, 6); LDA(pA, 7);
        if (t + 2 < NT) STAGE_B(1, t + 2);
        __builtin_amdgcn_s_barrier();
        asm volatile("s_waitcnt lgkmcnt(0)" ::: "memory");
        __builtin_amdgcn_sched_barrier(0);
        __builtin_amdgcn_s_setprio(1);
        QUAD(2);
        __builtin_amdgcn_s_setprio(0);
        __builtin_amdgcn_s_barrier();

        // ---- phase 3: stage A0(t+2) ; quad3 ; counted boundary wait ----
        if (t + 2 < NT) STAGE_A(0, t + 2);
        __builtin_amdgcn_s_barrier();
        __builtin_amdgcn_s_setprio(1);
        QUAD(3);
        __builtin_amdgcn_s_setprio(0);
        if (t == NT - 2) asm volatile("s_waitcnt vmcnt(0)" ::: "memory");
        else             asm volatile("s_waitcnt vmcnt(6)" ::: "memory");
        __builtin_amdgcn_s_barrier();
    }

    // ---- epilogue: C/D layout col=lane&15, row=(lane>>4)*4+reg [m89/m91] ----
#pragma unroll
    for (int mf = 0; mf < 8; ++mf) {
#pragma unroll
        for (int nf = 0; nf < 4; ++nf) {
            const size_t row = (size_t)(bm0 + wm * 128 + mf * 16 + kq * 4);
            const int col = bn0 + wn * 64 + nf * 16 + l15;
#pragma unroll
            for (int r = 0; r < 4; ++r)
                C[(row + r) * NN + col] = acc[mf][nf][r];
        }
    }
}

// ---- Fallback (insurance if ws too small): correct but slow ----
__global__ __launch_bounds__(256) void fallback_kernel(const float* __restrict__ x,
                                                       const float* __restrict__ w,
                                                       float* __restrict__ out) {
    int n = blockIdx.x * 256 + threadIdx.x;
    int m = blockIdx.y;
    float s = 0.f;
    for (int k = 0; k < KK; ++k) {
        float h = __half2float(__float2half(w[(size_t)k * NN + n]));
        float b = (h > 0.f) ? 1.f : ((h < 0.f) ? -1.f : 0.f);
        s += x[(size_t)m * KK + k] * b;
    }
    out[(size_t)m * NN + n] = s;
}

extern "C" void kernel_launch(void* const* d_in, const int* in_sizes, int n_in,
                              void* d_out, int out_size, void* d_ws, size_t ws_size,
                              hipStream_t stream) {
    const float* x = (const float*)d_in[0];
    const float* w = (const float*)d_in[1];
    if (n_in >= 2 && in_sizes[0] != MM * KK) {
        x = (const float*)d_in[1];
        w = (const float*)d_in[0];
    }
    float* out = (float*)d_out;

    const size_t xb_bytes = (size_t)MM * KK * 2;   // 64 MiB
    const size_t wt_bytes = (size_t)NN * KK * 2;   // 32 MiB

    if (ws_size >= xb_bytes + wt_bytes) {
        unsigned short* xb = (unsigned short*)d_ws;
        unsigned short* wt = (unsigned short*)((char*)d_ws + xb_bytes);

        int n4 = MM * KK / 4;
        cvt_x_kernel<<<(n4 + 255) / 256, 256, 0, stream>>>((const float4*)x, (ushort4*)xb, n4);
        binz_wt_kernel<<<dim3(NN / 64, KK / 64), 256, 0, stream>>>(w, wt);
        gemm_bin_kernel<<<dim3((NN / BN) * (MM / BM)), dim3(512), 0, stream>>>(xb, wt, out);
    } else {
        fallback_kernel<<<dim3(NN / 256, MM), 256, 0, stream>>>(x, w, out);
    }
}

// Round 2
// 468.017 us; speedup vs baseline: 1.2547x; 1.0003x over previous
//
#include <hip/hip_runtime.h>
#include <hip/hip_fp16.h>

#define MM 8192
#define NN 4096
#define KK 4096
#define BM 256
#define BN 256
#define BK 64
#define NT (KK / BK)   // 64 K-tiles

typedef __attribute__((ext_vector_type(8))) short bf16x8;
typedef __attribute__((ext_vector_type(4))) float floatx4;
typedef __attribute__((ext_vector_type(8))) unsigned short ushort8_t;

typedef const __attribute__((address_space(1))) unsigned int* gptr_t;
typedef __attribute__((address_space(3))) unsigned int* lptr_t;

// round-to-nearest-even fp32 -> bf16 bits (valid for non-NaN inputs)
__device__ __forceinline__ unsigned short f2bf(float f) {
    unsigned u = __builtin_bit_cast(unsigned, f);
    u += 0x7FFFu + ((u >> 16) & 1u);
    return (unsigned short)(u >> 16);
}

__device__ __forceinline__ unsigned short sign_bf16(float f) {
    // sign(clip(fp16(f),-1,1)) == sign(fp16(f)); fp16 rounds |f|<2^-25 to 0
    float h = __half2float(__float2half(f));
    return (h > 0.f) ? 0x3F80u : ((h < 0.f) ? 0xBF80u : 0u);
}

// ---- Prepass 1: x fp32 -> bf16 (row-major M x K), 32B loads / 16B stores ----
__global__ __launch_bounds__(256) void cvt_x_kernel(const float4* __restrict__ x4,
                                                    ushort8_t* __restrict__ o8, int n8) {
    int i = blockIdx.x * 256 + threadIdx.x;
    if (i >= n8) return;
    float4 a = x4[2 * i];
    float4 b = x4[2 * i + 1];
    ushort8_t o;
    o[0] = f2bf(a.x); o[1] = f2bf(a.y); o[2] = f2bf(a.z); o[3] = f2bf(a.w);
    o[4] = f2bf(b.x); o[5] = f2bf(b.y); o[6] = f2bf(b.z); o[7] = f2bf(b.w);
    o8[i] = o;
}

// ---- Prepass 2: w (K x N fp32) -> sign(fp16(w)) bf16, transposed to N x K ----
__global__ __launch_bounds__(256) void binz_wt_kernel(const float* __restrict__ w,
                                                      unsigned short* __restrict__ wt) {
    __shared__ unsigned short tileT[64][72];   // [n][k]; 144B row stride
    const int n0 = blockIdx.x * 64;
    const int k0 = blockIdx.y * 64;
    const int t  = threadIdx.x;
    {
        const int c4 = t & 15;
        const int rb = t >> 4;
#pragma unroll
        for (int i = 0; i < 4; ++i) {
            int r = rb + i * 16;
            float4 v = *(const float4*)&w[(size_t)(k0 + r) * NN + n0 + c4 * 4];
            tileT[c4 * 4 + 0][r] = sign_bf16(v.x);
            tileT[c4 * 4 + 1][r] = sign_bf16(v.y);
            tileT[c4 * 4 + 2][r] = sign_bf16(v.z);
            tileT[c4 * 4 + 3][r] = sign_bf16(v.w);
        }
    }
    __syncthreads();
    {
        const int g  = t & 7;
        const int nb = t >> 3;
#pragma unroll
        for (int i = 0; i < 2; ++i) {
            int n = nb + i * 32;
            *(ushort8_t*)&wt[(size_t)(n0 + n) * KK + k0 + g * 8] =
                *(const ushort8_t*)&tileT[n][g * 8];
        }
    }
}

// ---- GEMM: 256x256, BK=64, 8 waves, 4-phase/K-tile with read-ahead pipeline ----
// LDS: A slots [buf][half] 16 KiB @0..64K, B same @64K..128K. 16B-chunk XOR swizzle.
// Quads (16 MFMA each): q0=mf0-3xnf01, q1=mf4-7xnf01, q2=mf0-3xnf23, q3=mf4-7xnf23.
// Read-ahead: ph3(t-1): af[0-3]+bfr[0,1] (12 rd, AFTER vmcnt+barrier); ph0: af[4-7]
// (8 rd); ph1: bfr[2,3] (4 rd); ph2: none. MFMA at ph p waits lgkmcnt(reads issued
// at p), so prior phase's reads are done but current ones stream under the MFMA.
// Stage ledger: ph0: A1(t+1); ph1: B0(t+2); ph3: B1(t+2),A0(t+2); boundary vmcnt(6)
// mid-ph3 (vmcnt(0) at t==NT-2), then barrier, THEN next-tile reads (cross-wave DMA
// landing). WAR check: B1(t) reads (ph1) complete at ph2's lgkmcnt(0), before
// B1(t+2) stage at ph3 -- this is why B1's stage moved out of ph2.
__global__ __launch_bounds__(512, 2) void gemm_bin_kernel(const unsigned short* __restrict__ A,
                                                          const unsigned short* __restrict__ Bt,
                                                          float* __restrict__ C) {
    __shared__ __align__(16) char lds[131072];

    const int tid    = threadIdx.x;
    const int lane   = tid & 63;
    const int wave   = tid >> 6;                       // 0..7
    const int wave_u = __builtin_amdgcn_readfirstlane(wave);
    const int wm     = wave >> 2;                      // 0..1  (128 M-rows each)
    const int wn     = wave & 3;                       // 0..3  (64 N-cols each)
    const int l15    = lane & 15;
    const int kq     = lane >> 4;                      // 0..3

    // XCD-bijective swizzle: 512 wgs, 8 XCDs, 64 contiguous per XCD
    const int bid = blockIdx.x;
    const int wg  = (bid & 7) * 64 + (bid >> 3);
    const int bn0 = (wg & 15) * BN;
    const int bm0 = (wg >> 4) * BM;

    // staging: chunk = tid; row = tid>>3, cg = tid&7; inverse-swizzled source col
    const int r0 = tid >> 3;                           // 0..63
    const int c0 = (tid & 7) ^ (r0 & 7);
    const char* gA = (const char*)A;
    const char* gB = (const char*)Bt;
    const size_t aoff = (size_t)(bm0 + r0) * (KK * 2) + (size_t)c0 * 16;
    const size_t boff = (size_t)(bn0 + r0) * (KK * 2) + (size_t)c0 * 16;

    __attribute__((address_space(3))) char* lds3 =
        (__attribute__((address_space(3))) char*)lds;
    const int dstw = wave_u * 1024;

    // ds_read swizzled col offsets for k-slice ks: ((ks*4+kq) ^ (lane&7)) * 16
    const int aco0 = ((0 * 4 + kq) ^ (lane & 7)) * 16;
    const int aco1 = ((1 * 4 + kq) ^ (lane & 7)) * 16;
    const char* ldsA_l = lds + l15 * 128;
    const char* ldsB_l = lds + 65536 + ((wn & 1) * 64 + l15) * 128;
    const char* pA0 = ldsA_l + (0 * 2 + wm) * 16384;
    const char* pA1 = ldsA_l + (1 * 2 + wm) * 16384;
    const char* pB0 = ldsB_l + (0 * 2 + (wn >> 1)) * 16384;
    const char* pB1 = ldsB_l + (1 * 2 + (wn >> 1)) * 16384;

    floatx4 acc[8][4] = {};
    bf16x8 af[8][2];
    bf16x8 bfr[4][2];

    auto STAGE_A = [&](int h, int kt) {
        const int slot = (kt & 1) * 2 + h;
        const char* s0 = gA + aoff + (size_t)h * (128 * KK * 2) + (size_t)kt * (BK * 2);
        __builtin_amdgcn_global_load_lds((gptr_t)s0,
            (lptr_t)(lds3 + slot * 16384 + dstw), 16, 0, 0);
        __builtin_amdgcn_global_load_lds((gptr_t)(s0 + (size_t)64 * KK * 2),
            (lptr_t)(lds3 + slot * 16384 + 8192 + dstw), 16, 0, 0);
    };
    auto STAGE_B = [&](int h, int kt) {
        const int slot = (kt & 1) * 2 + h;
        const char* s0 = gB + boff + (size_t)h * (128 * KK * 2) + (size_t)kt * (BK * 2);
        __builtin_amdgcn_global_load_lds((gptr_t)s0,
            (lptr_t)(lds3 + 65536 + slot * 16384 + dstw), 16, 0, 0);
        __builtin_amdgcn_global_load_lds((gptr_t)(s0 + (size_t)64 * KK * 2),
            (lptr_t)(lds3 + 65536 + slot * 16384 + 8192 + dstw), 16, 0, 0);
    };
    auto LDA = [&](const char* pAp, int mf) {
        af[mf][0] = *(const bf16x8*)(pAp + aco0 + mf * 2048);
        af[mf][1] = *(const bf16x8*)(pAp + aco1 + mf * 2048);
    };
    auto LDB = [&](const char* pBp, int nf) {
        bfr[nf][0] = *(const bf16x8*)(pBp + aco0 + nf * 2048);
        bfr[nf][1] = *(const bf16x8*)(pBp + aco1 + nf * 2048);
    };
    auto QUAD8 = [&](int mb, int nb) {   // 4 mf x 2 nf x 2 ks = 16 MFMA
#pragma unroll
        for (int mi = 0; mi < 4; ++mi)
#pragma unroll
            for (int nj = 0; nj < 2; ++nj)
#pragma unroll
                for (int ks = 0; ks < 2; ++ks)
                    acc[mb + mi][nb + nj] = __builtin_amdgcn_mfma_f32_16x16x32_bf16(
                        af[mb + mi][ks], bfr[nb + nj][ks], acc[mb + mi][nb + nj], 0, 0, 0);
    };

#define WAITL(n) do { asm volatile("s_waitcnt lgkmcnt(" #n ")" ::: "memory"); \
                      __builtin_amdgcn_sched_barrier(0); } while (0)

    // ---- prologue: stage tile0 (4 halves) + tile1 (B0,B1,A0); wait tile0 ----
    STAGE_B(0, 0); STAGE_B(1, 0); STAGE_A(0, 0); STAGE_A(1, 0);
    STAGE_B(0, 1); STAGE_B(1, 1); STAGE_A(0, 1);
    asm volatile("s_waitcnt vmcnt(6)" ::: "memory");
    __builtin_amdgcn_s_barrier();
    // initial read-ahead for q0 of tile 0
    LDA(pA0, 0); LDA(pA0, 1); LDA(pA0, 2); LDA(pA0, 3);
    LDB(pB0, 0); LDB(pB0, 1);

#define TILE_BODY(t, pAc, pBc, pAn, pBn)                                        \
    {                                                                           \
        /* ph0: read af[4-7]; stage A1(t+1); quad0 */                           \
        LDA(pAc, 4); LDA(pAc, 5); LDA(pAc, 6); LDA(pAc, 7);                     \
        if ((t) + 1 < NT) STAGE_A(1, (t) + 1);                                  \
        __builtin_amdgcn_s_barrier();                                           \
        WAITL(8);                                                               \
        __builtin_amdgcn_s_setprio(1);                                          \
        QUAD8(0, 0);                                                            \
        __builtin_amdgcn_s_setprio(0);                                          \
        __builtin_amdgcn_s_barrier();                                           \
        /* ph1: read bfr[2,3]; stage B0(t+2); quad1 */                          \
        LDB(pBc, 2); LDB(pBc, 3);                                               \
        if ((t) + 2 < NT) STAGE_B(0, (t) + 2);                                  \
        __builtin_amdgcn_s_barrier();                                           \
        WAITL(4);                                                               \
        __builtin_amdgcn_s_setprio(1);                                          \
        QUAD8(4, 0);                                                            \
        __builtin_amdgcn_s_setprio(0);                                          \
        __builtin_amdgcn_s_barrier();                                           \
        /* ph2: quad2 (operands from ph1; nothing new issued) */                \
        WAITL(0);                                                               \
        __builtin_amdgcn_s_setprio(1);                                          \
        QUAD8(0, 2);                                                            \
        __builtin_amdgcn_s_setprio(0);                                          \
        __builtin_amdgcn_s_barrier();                                           \
        /* ph3: stage B1,A0(t+2); boundary vmcnt; barrier; next-tile reads; q3 */ \
        if ((t) + 2 < NT) { STAGE_B(1, (t) + 2); STAGE_A(0, (t) + 2); }         \
        if ((t) == NT - 2) { asm volatile("s_waitcnt vmcnt(0)" ::: "memory"); } \
        else               { asm volatile("s_waitcnt vmcnt(6)" ::: "memory"); } \
        __builtin_amdgcn_s_barrier();                                           \
        LDA(pAn, 0); LDA(pAn, 1); LDA(pAn, 2); LDA(pAn, 3);                     \
        LDB(pBn, 0); LDB(pBn, 1);                                               \
        WAITL(12);                                                              \
        __builtin_amdgcn_s_setprio(1);                                          \
        QUAD8(4, 2);                                                            \
        __builtin_amdgcn_s_setprio(0);                                          \
        __builtin_amdgcn_s_barrier();                                           \
    }

    for (int tb = 0; tb < NT; tb += 2) {
        TILE_BODY(tb,     pA0, pB0, pA1, pB1);
        TILE_BODY(tb + 1, pA1, pB1, pA0, pB0);
    }
#undef TILE_BODY
#undef WAITL

    // ---- epilogue: C/D layout col=lane&15, row=(lane>>4)*4+reg [m89/m91] ----
#pragma unroll
    for (int mf = 0; mf < 8; ++mf) {
#pragma unroll
        for (int nf = 0; nf < 4; ++nf) {
            const size_t row = (size_t)(bm0 + wm * 128 + mf * 16 + kq * 4);
            const int col = bn0 + wn * 64 + nf * 16 + l15;
#pragma unroll
            for (int r = 0; r < 4; ++r)
                C[(row + r) * NN + col] = acc[mf][nf][r];
        }
    }
}

// ---- Fallback (insurance if ws too small): correct but slow ----
__global__ __launch_bounds__(256) void fallback_kernel(const float* __restrict__ x,
                                                       const float* __restrict__ w,
                                                       float* __restrict__ out) {
    int n = blockIdx.x * 256 + threadIdx.x;
    int m = blockIdx.y;
    float s = 0.f;
    for (int k = 0; k < KK; ++k) {
        float h = __half2float(__float2half(w[(size_t)k * NN + n]));
        float b = (h > 0.f) ? 1.f : ((h < 0.f) ? -1.f : 0.f);
        s += x[(size_t)m * KK + k] * b;
    }
    out[(size_t)m * NN + n] = s;
}

extern "C" void kernel_launch(void* const* d_in, const int* in_sizes, int n_in,
                              void* d_out, int out_size, void* d_ws, size_t ws_size,
                              hipStream_t stream) {
    const float* x = (const float*)d_in[0];
    const float* w = (const float*)d_in[1];
    if (n_in >= 2 && in_sizes[0] != MM * KK) {
        x = (const float*)d_in[1];
        w = (const float*)d_in[0];
    }
    float* out = (float*)d_out;

    const size_t xb_bytes = (size_t)MM * KK * 2;   // 64 MiB
    const size_t wt_bytes = (size_t)NN * KK * 2;   // 32 MiB

    if (ws_size >= xb_bytes + wt_bytes) {
        unsigned short* xb = (unsigned short*)d_ws;
        unsigned short* wt = (unsigned short*)((char*)d_ws + xb_bytes);

        int n8 = MM * KK / 8;
        cvt_x_kernel<<<(n8 + 255) / 256, 256, 0, stream>>>((const float4*)x, (ushort8_t*)xb, n8);
        binz_wt_kernel<<<dim3(NN / 64, KK / 64), 256, 0, stream>>>(w, wt);
        gemm_bin_kernel<<<dim3((NN / BN) * (MM / BM)), dim3(512), 0, stream>>>(xb, wt, out);
    } else {
        fallback_kernel<<<dim3(NN / 256, MM), 256, 0, stream>>>(x, w, out);
    }
}